// Round 18
// baseline (313.361 us; speedup 1.0000x reference)
//
#include <hip/hip_runtime.h>
#include <hip/hip_bf16.h>
#include <stdint.h>

#define NH 16
#define NKV 8
#define HD 128
#define BB 4
#define SS 1024
#define CTXL 2048
#define LT 3072
#define HID 2048
#define QKVN 4096
#define MROWS 4096

typedef __hip_bfloat16 bf16;
using f32x4 = __attribute__((ext_vector_type(4))) float;
using s16x8 = __attribute__((ext_vector_type(8))) short;

#define MFMA(a, b, c) __builtin_amdgcn_mfma_f32_16x16x32_bf16((a), (b), (c), 0, 0, 0)

__device__ __forceinline__ void gload_lds16(const void* g, void* l) {
  __builtin_amdgcn_global_load_lds((const __attribute__((address_space(1))) void*)g,
                                   (__attribute__((address_space(3))) void*)l, 16, 0, 0);
}

__device__ __forceinline__ void store_bf8(bf16* dst, const float* f) {
  bf16 tmp[8];
#pragma unroll
  for (int j = 0; j < 8; ++j) tmp[j] = __float2bfloat16(f[j]);
  __builtin_memcpy((void*)dst, (const void*)tmp, 16);
}

__device__ __forceinline__ float bf2f(short x) {
  unsigned int u = ((unsigned int)(unsigned short)x) << 16;
  float f;
  __builtin_memcpy(&f, &u, 4);
  return f;
}

// ---------------- prep1 (512 thr): only what gemm_qkv needs ---------------
// [0,2048)      cvt hs -> Hb
// [2048,6144)   transpose Wqkv -> WqT (2 tiles/block)
// [6144,6272)   rope table
#define P1_CVT 2048
#define P1_WQ (P1_CVT + 4096)
#define P1_RT (P1_WQ + 128)

__global__ void prep1(const float* __restrict__ hs, const float* __restrict__ Wqkv,
                      const int* __restrict__ pid, bf16* __restrict__ Hb,
                      bf16* __restrict__ WqT, float* __restrict__ cosT,
                      float* __restrict__ sinT) {
  __shared__ float tile[2][32][33];
  const int blk = blockIdx.x, t = threadIdx.x;
  if (blk < P1_CVT) {
    size_t tid = (size_t)blk * 512 + t;
    const float4* p = (const float4*)(hs + tid * 8);
    float4 a = p[0], b = p[1];
    float f[8] = {a.x, a.y, a.z, a.w, b.x, b.y, b.z, b.w};
    store_bf8(Hb + tid * 8, f);
  } else if (blk < P1_WQ) {
    int j2 = (blk - P1_CVT) * 2 + (t >> 8);
    int c0 = (j2 & 127) * 32, r0 = (j2 >> 7) * 32;  // R=2048 C=4096
    int tt = t & 255, tx = tt & 31, ty = tt >> 5, sl = t >> 8;
#pragma unroll
    for (int i = 0; i < 32; i += 8)
      tile[sl][ty + i][tx] = Wqkv[(size_t)(r0 + ty + i) * QKVN + c0 + tx];
    __syncthreads();
#pragma unroll
    for (int i = 0; i < 32; i += 8)
      WqT[(size_t)(c0 + ty + i) * HID + r0 + tx] =
          __float2bfloat16(tile[sl][tx][ty + i]);
  } else {
    int tid = (blk - P1_WQ) * 512 + t;  // S*64
    int j = tid & 63, s = tid >> 6;
    int sec = (j < 8) ? 0 : (j < 16) ? 1 : (j < 40) ? 2 : 3;
    float pos = (float)pid[sec * SS + s];
    float inv = __expf(-(float)j * 0.14391156831212787f);  // ln(10000)/64
    float a = pos * inv;
    cosT[tid] = cosf(a);
    sinT[tid] = sinf(a);
  }
}

// ---------------- QKV GEMM (4-phase) + merged independent prep ------------
// 1D grid, 8448 blocks:
//   [0,256)      256x256 GEMM tiles (4-phase/K-tile, counted vmcnt(2))
//   [256,2304)   ctx_k copy -> Kfull          (memory-bound, co-resident)
//   [2304,6400)  ctx_v transpose -> Vt (2 tiles/block)
//   [6400,8448)  Wo transpose -> WoT   (2 tiles/block)
// GEMM blocks dispatch first and pin the CUs; prep blocks (8.5 KB LDS) fill
// the spare LDS/wave slots and stream HBM traffic under the compute.
#define GQ_CK 256
#define GQ_CV 2304
#define GQ_WO 6400
#define GQ_TOT 8448

__global__ __launch_bounds__(512, 1) void gemm_qkv(
    const bf16* __restrict__ A, const bf16* __restrict__ BT,
    bf16* __restrict__ qkv, bf16* __restrict__ Kf, bf16* __restrict__ Vt,
    const float* __restrict__ cosT, const float* __restrict__ sinT,
    const float* __restrict__ Wo, bf16* __restrict__ WoT,
    const float* __restrict__ ck, const float* __restrict__ cv) {
  __shared__ __attribute__((aligned(16))) char smem[132096];
  const int id = blockIdx.x;
  const int t = threadIdx.x;

  if (id >= GQ_CK) {
    if (id < GQ_CV) {
      // ctx_k [b][l][h][d] f32 -> Kfull [b][h][l][d] bf16
      int tid = (id - GQ_CK) * 512 + t;
      int d8 = tid & 15, l = (tid >> 4) & 2047, h = (tid >> 15) & 7, b = tid >> 18;
      const float* s = ck + (((size_t)b * CTXL + l) * NKV + h) * HD + d8 * 8;
      const float4* p = (const float4*)s;
      float4 a = p[0], bb = p[1];
      float f[8] = {a.x, a.y, a.z, a.w, bb.x, bb.y, bb.z, bb.w};
      store_bf8(Kf + (((size_t)(b * NKV + h)) * LT + l) * HD + d8 * 8, f);
    } else if (id < GQ_WO) {
      // ctx_v [b][l][h][d] f32 -> Vt [b][h][d][l] bf16 (2 tiles/block)
      float(*tile)[32][33] = (float(*)[32][33])smem;
      int j2 = (id - GQ_CV) * 2 + (t >> 8);
      int l0 = (j2 & 63) * 32, d0 = ((j2 >> 6) & 3) * 32;
      int bz = j2 >> 8, b = bz >> 3, h = bz & 7;
      int tt = t & 255, tx = tt & 31, ty = tt >> 5, sl = t >> 8;
#pragma unroll
      for (int i = 0; i < 32; i += 8)
        tile[sl][ty + i][tx] =
            cv[(((size_t)b * CTXL + l0 + ty + i) * NKV + h) * HD + d0 + tx];
      __syncthreads();
#pragma unroll
      for (int i = 0; i < 32; i += 8)
        Vt[(((size_t)(b * NKV + h)) * HD + d0 + ty + i) * LT + l0 + tx] =
            __float2bfloat16(tile[sl][tx][ty + i]);
    } else {
      // Wo transpose (2048x2048, 2 tiles/block)
      float(*tile)[32][33] = (float(*)[32][33])smem;
      int j2 = (id - GQ_WO) * 2 + (t >> 8);
      int c0 = (j2 & 63) * 32, r0 = (j2 >> 6) * 32;
      int tt = t & 255, tx = tt & 31, ty = tt >> 5, sl = t >> 8;
#pragma unroll
      for (int i = 0; i < 32; i += 8)
        tile[sl][ty + i][tx] = Wo[(size_t)(r0 + ty + i) * 2048 + c0 + tx];
      __syncthreads();
#pragma unroll
      for (int i = 0; i < 32; i += 8)
        WoT[(size_t)(c0 + ty + i) * 2048 + r0 + tx] =
            __float2bfloat16(tile[sl][tx][ty + i]);
    }
    return;
  }

  // ---------------- GEMM path (id < 256) ----------------
  bf16* lds = (bf16*)smem;
#define lAp(s, hf) (lds + ((s)*2 + (hf)) * 8192)
#define lBp(s, hf) (lds + 32768 + ((s)*2 + (hf)) * 8192)
  const int K = HID;
  const int lane = t & 63, w = t >> 6;
  const int wr = w >> 2, wc = w & 3;  // 2M x 4N
  const int lrow = lane & 15, kgrp = lane >> 4;
  const int lin = id;
  const int swz = (lin & 7) * 32 + (lin >> 3);
  const int bx = swz & 15, by = swz >> 4;
  const int m0 = by * 256, n0 = bx * 256;
  const f32x4 fz = {0.f, 0.f, 0.f, 0.f};
  f32x4 acc[8][4];
#pragma unroll
  for (int i = 0; i < 8; ++i)
#pragma unroll
    for (int j = 0; j < 4; ++j) acc[i][j] = fz;

#define STAGEH(sslot, skt, isB, shalf)                                        \
  do {                                                                        \
    _Pragma("unroll") for (int c = 0; c < 2; ++c) {                           \
      int row = w * 16 + c * 8 + (lane >> 3);                                 \
      int sch = (lane & 7) ^ (lane >> 3);                                     \
      const bf16* src =                                                       \
          (isB) ? (BT + (size_t)(n0 + (shalf)*128 + row) * K + (skt)*64 + sch * 8) \
                : (A + (size_t)(m0 + (shalf)*128 + row) * K + (skt)*64 + sch * 8); \
      bf16* dst = ((isB) ? lBp((sslot), (shalf)) : lAp((sslot), (shalf))) +   \
                  (w * 16 + c * 8) * 64;                                      \
      gload_lds16(src, dst);                                                  \
    }                                                                         \
  } while (0)

#define PHASE(cslot, qm, qn, DOST, sslot, skt, isB, shalf)                    \
  do {                                                                        \
    if (DOST) {                                                               \
      STAGEH(sslot, skt, isB, shalf);                                         \
      asm volatile("s_waitcnt vmcnt(2)" ::: "memory");                        \
    } else {                                                                  \
      asm volatile("s_waitcnt vmcnt(0)" ::: "memory");                        \
    }                                                                         \
    __builtin_amdgcn_s_barrier();                                             \
    __builtin_amdgcn_sched_barrier(0);                                        \
    s16x8 af_[4][2], bf_[2][2];                                               \
    _Pragma("unroll") for (int fi = 0; fi < 4; ++fi)                          \
        _Pragma("unroll") for (int ks = 0; ks < 2; ++ks) {                    \
      int row = (qm)*64 + fi * 16 + lrow;                                     \
      af_[fi][ks] = *(const s16x8*)&lAp(cslot, wr)[row * 64 +                 \
                                                   ((ks * 4 + kgrp) ^ (lrow & 7)) * 8]; \
    }                                                                         \
    _Pragma("unroll") for (int fj = 0; fj < 2; ++fj)                          \
        _Pragma("unroll") for (int ks = 0; ks < 2; ++ks) {                    \
      int col = (wc & 1) * 64 + (qn)*32 + fj * 16 + lrow;                     \
      bf_[fj][ks] = *(const s16x8*)&lBp(cslot, wc >> 1)[col * 64 +            \
                                                        ((ks * 4 + kgrp) ^ (lrow & 7)) * 8]; \
    }                                                                         \
    asm volatile("s_waitcnt lgkmcnt(0)" ::: "memory");                        \
    __builtin_amdgcn_sched_barrier(0);                                        \
    __builtin_amdgcn_s_setprio(1);                                            \
    _Pragma("unroll") for (int fi = 0; fi < 4; ++fi)                          \
        _Pragma("unroll") for (int fj = 0; fj < 2; ++fj)                      \
            _Pragma("unroll") for (int ks = 0; ks < 2; ++ks)                  \
                acc[(qm)*4 + fi][(qn)*2 + fj] =                               \
        MFMA(af_[fi][ks], bf_[fj][ks], acc[(qm)*4 + fi][(qn)*2 + fj]);        \
    __builtin_amdgcn_s_setprio(0);                                            \
    __builtin_amdgcn_s_barrier();                                             \
  } while (0)

  STAGEH(0, 0, 0, 0);
  STAGEH(0, 0, 1, 0);
  STAGEH(0, 0, 0, 1);
  STAGEH(0, 0, 1, 1);
  asm volatile("s_waitcnt vmcnt(0)" ::: "memory");
  __builtin_amdgcn_s_barrier();

  for (int kt = 0; kt < 32; kt += 2) {
    PHASE(0, 0, 0, true, 1, kt + 1, 0, 0);
    PHASE(0, 1, 0, true, 1, kt + 1, 1, 0);
    PHASE(0, 0, 1, true, 1, kt + 1, 0, 1);
    PHASE(0, 1, 1, true, 1, kt + 1, 1, 1);
    const bool d2 = (kt + 2 < 32);
    PHASE(1, 0, 0, d2, 0, kt + 2, 0, 0);
    PHASE(1, 1, 0, d2, 0, kt + 2, 1, 0);
    PHASE(1, 0, 1, d2, 0, kt + 2, 0, 1);
    PHASE(1, 1, 1, d2, 0, kt + 2, 1, 1);
  }
#undef PHASE
#undef STAGEH

  const int b = m0 >> 10, s0 = m0 & 1023;
  if (n0 < 2048) {
#pragma unroll
    for (int fm = 0; fm < 8; ++fm)
#pragma unroll
      for (int fn = 0; fn < 4; ++fn)
#pragma unroll
        for (int r = 0; r < 4; ++r) {
          int row = m0 + wr * 128 + fm * 16 + kgrp * 4 + r;
          int col = n0 + wc * 64 + fn * 16 + lrow;
          qkv[(size_t)row * QKVN + col] = __float2bfloat16(acc[fm][fn][r]);
        }
  } else {
    float* stage = (float*)smem;  // [256][129] f32 = 132096 B
#pragma unroll 1
    for (int hh = 0; hh < 2; ++hh) {
      __syncthreads();
      if ((wc >> 1) == hh) {
#pragma unroll
        for (int fm = 0; fm < 8; ++fm)
#pragma unroll
          for (int fn = 0; fn < 4; ++fn)
#pragma unroll
            for (int r = 0; r < 4; ++r) {
              int rr = wr * 128 + fm * 16 + kgrp * 4 + r;
              int cc = (wc & 1) * 64 + fn * 16 + lrow;
              stage[rr * 129 + cc] = acc[fm][fn][r];
            }
      }
      __syncthreads();
      if (n0 < 3072) {
        int h = ((n0 - 2048) >> 7) + hh;
#pragma unroll 4
        for (int it = 0; it < 32; ++it) {
          int idx = it * 512 + t;
          int r = idx >> 6, j = idx & 63;
          float x1 = stage[r * 129 + j], x2 = stage[r * 129 + j + 64];
          int s = s0 + r;
          float c = cosT[s * 64 + j], sn = sinT[s * 64 + j];
          bf16* dst = Kf + ((size_t)(b * NKV + h) * LT + CTXL + s) * HD;
          dst[j] = __float2bfloat16(x1 * c - x2 * sn);
          dst[j + 64] = __float2bfloat16(x2 * c + x1 * sn);
        }
      } else {
        int h = ((n0 - 3072) >> 7) + hh;
#pragma unroll 4
        for (int it = 0; it < 64; ++it) {
          int idx = it * 512 + t;
          int soff = idx & 255, d = idx >> 8;
          Vt[((size_t)(b * NKV + h) * HD + d) * LT + CTXL + s0 + soff] =
              __float2bfloat16(stage[soff * 129 + d]);
        }
      }
    }
  }
#undef lAp
#undef lBp
}

// ---------------- GEMM: C[M][N] = A[M][K] * BT[N][K]^T (out-proj) ---------
template <typename OT>
__global__ __launch_bounds__(512, 1) void gemm_bt(const bf16* __restrict__ A,
                                                  const bf16* __restrict__ BT,
                                                  OT* __restrict__ C, int M, int N,
                                                  int K) {
  __shared__ __attribute__((aligned(16))) bf16 lA[3][256][64];  // 96 KB
  __shared__ __attribute__((aligned(16))) bf16 lB[3][128][64];  // 48 KB
  const int t = threadIdx.x;
  const int lane = t & 63, w = t >> 6;
  const int wr = w >> 1, wc = w & 1;
  const int lrow = lane & 15, kgrp = lane >> 4;
  const int rchk = lrow & 7;
  const int lin = blockIdx.y * gridDim.x + blockIdx.x;
  const int qq = (gridDim.x * gridDim.y) >> 3;
  const int swz = (lin & 7) * qq + (lin >> 3);
  const int bx = swz % gridDim.x, by = swz / gridDim.x;
  const int m0 = by * 256, n0 = bx * 128;
  const int srow = lane >> 3;
  const int schk = (lane & 7) ^ srow;
  const f32x4 fz = {0.f, 0.f, 0.f, 0.f};
  f32x4 acc[4][4];
#pragma unroll
  for (int i = 0; i < 4; ++i)
#pragma unroll
    for (int j = 0; j < 4; ++j) acc[i][j] = fz;
  const int NTK = K >> 6;

#define GSTAGE(ib, kt)                                                      \
  do {                                                                      \
    _Pragma("unroll") for (int c = 0; c < 4; ++c) {                         \
      int ra = c * 64 + w * 8 + srow;                                       \
      gload_lds16(A + (size_t)(m0 + ra) * K + (kt)*64 + schk * 8,           \
                  &lA[ib][c * 64 + w * 8][0]);                              \
    }                                                                       \
    _Pragma("unroll") for (int c = 0; c < 2; ++c) {                         \
      int rb = c * 64 + w * 8 + srow;                                       \
      gload_lds16(BT + (size_t)(n0 + rb) * K + (kt)*64 + schk * 8,          \
                  &lB[ib][c * 64 + w * 8][0]);                              \
    }                                                                       \
  } while (0)

  GSTAGE(0, 0);
  GSTAGE(1, 1);
  int ib = 0;
  for (int kt = 0; kt < NTK; ++kt) {
    if (kt + 1 < NTK)
      asm volatile("s_waitcnt vmcnt(6) lgkmcnt(0)" ::: "memory");
    else
      asm volatile("s_waitcnt vmcnt(0) lgkmcnt(0)" ::: "memory");
    __builtin_amdgcn_s_barrier();
    __builtin_amdgcn_sched_barrier(0);
    if (kt + 2 < NTK) {
      int ib2 = ib + 2;
      if (ib2 >= 3) ib2 -= 3;
      GSTAGE(ib2, kt + 2);
    }
#pragma unroll
    for (int kk = 0; kk < 2; ++kk) {
      s16x8 af[4], bf[4];
#pragma unroll
      for (int i = 0; i < 4; ++i)
        af[i] = *(const s16x8*)&lA[ib][wr * 64 + i * 16 + lrow]
                                     [(((kk << 2) + kgrp) ^ rchk) * 8];
#pragma unroll
      for (int j = 0; j < 4; ++j)
        bf[j] = *(const s16x8*)&lB[ib][wc * 64 + j * 16 + lrow]
                                     [(((kk << 2) + kgrp) ^ rchk) * 8];
      __builtin_amdgcn_s_setprio(1);
#pragma unroll
      for (int i = 0; i < 4; ++i)
#pragma unroll
        for (int j = 0; j < 4; ++j) acc[i][j] = MFMA(af[i], bf[j], acc[i][j]);
      __builtin_amdgcn_s_setprio(0);
    }
    ++ib;
    if (ib >= 3) ib = 0;
  }
#undef GSTAGE

#pragma unroll
  for (int i = 0; i < 4; ++i)
#pragma unroll
    for (int j = 0; j < 4; ++j)
#pragma unroll
      for (int r = 0; r < 4; ++r) {
        int row = m0 + wr * 64 + i * 16 + kgrp * 4 + r;
        int col = n0 + wc * 64 + j * 16 + lrow;
        float v = acc[i][j][r];
        if constexpr (sizeof(OT) == 2)
          C[(size_t)row * N + col] = __float2bfloat16(v);
        else
          C[(size_t)row * N + col] = v;
      }
}

// ---------------- flash attention (KVBLK=128, K+V double-buffered) --------
#define PSTR 72  // P row stride in elements: 144B = 16B-aligned
#define KVB 128
#define NTT 24   // LT / 128
#define SCALE2 0.1275174335919605f  // scale * log2(e)

__global__ __launch_bounds__(512, 2) void flash_attn(
    const bf16* __restrict__ qkv, const float* __restrict__ cosT,
    const float* __restrict__ sinT, const bf16* __restrict__ Kf,
    const bf16* __restrict__ Vt, bf16* __restrict__ O) {
  __shared__ __attribute__((aligned(16))) bf16 Kl[2][128][128];     // 64 KB
  __shared__ __attribute__((aligned(16))) bf16 Vl[2][128][128];     // 64 KB
  __shared__ __attribute__((aligned(16))) bf16 P_lds[8][16][PSTR];  // 18 KB
  const int t = threadIdx.x, lane = t & 63, w = t >> 6;
  // XCD panel swizzle (bijective): b=id>>6, hk=id&7, h=(hk<<1)|bit5, qb=bits3-4
  const int id = blockIdx.x;
  const int b = id >> 6, hk = id & 7;
  const int h = (hk << 1) | ((id >> 5) & 1);
  const int qb = (id >> 3) & 3;
  const int lrow = lane & 15, kgrp = lane >> 4;
  const bf16* Kp = Kf + (size_t)(b * NKV + hk) * LT * HD;
  const bf16* Vp = Vt + (size_t)(b * NKV + hk) * HD * LT;

  // prologue: load Q rows from qkv and apply RoPE in-register
  s16x8 qf[2][4];
#pragma unroll
  for (int f = 0; f < 2; ++f) {
    int srw_i = qb * 256 + w * 32 + f * 16 + lrow;
    const bf16* qrow = qkv + ((size_t)b * SS + srw_i) * QKVN + h * HD;
    s16x8 qr[4];
#pragma unroll
    for (int kd = 0; kd < 4; ++kd)
      qr[kd] = *(const s16x8*)&qrow[kd * 32 + kgrp * 8];
    const float* crow = cosT + srw_i * 64 + kgrp * 8;
    const float* srow = sinT + srw_i * 64 + kgrp * 8;
    float qv[4][8], cc[2][8], ssv[2][8];
#pragma unroll
    for (int kd = 0; kd < 4; ++kd)
#pragma unroll
      for (int j = 0; j < 8; ++j) qv[kd][j] = bf2f(qr[kd][j]);
#pragma unroll
    for (int g = 0; g < 2; ++g)
#pragma unroll
      for (int j = 0; j < 8; ++j) {
        cc[g][j] = crow[g * 32 + j];
        ssv[g][j] = srow[g * 32 + j];
      }
    bf16 o[4][8];
#pragma unroll
    for (int j = 0; j < 8; ++j) {
      o[0][j] = __float2bfloat16(qv[0][j] * cc[0][j] - qv[2][j] * ssv[0][j]);
      o[1][j] = __float2bfloat16(qv[1][j] * cc[1][j] - qv[3][j] * ssv[1][j]);
      o[2][j] = __float2bfloat16(qv[2][j] * cc[0][j] + qv[0][j] * ssv[0][j]);
      o[3][j] = __float2bfloat16(qv[3][j] * cc[1][j] + qv[1][j] * ssv[1][j]);
    }
#pragma unroll
    for (int kd = 0; kd < 4; ++kd) __builtin_memcpy(&qf[f][kd], o[kd], 16);
  }

  const f32x4 fz = {0.f, 0.f, 0.f, 0.f};
  f32x4 acc[2][8];
#pragma unroll
  for (int f = 0; f < 2; ++f)
#pragma unroll
    for (int i = 0; i < 8; ++i) acc[f][i] = fz;
  float m_[2] = {-1e30f, -1e30f}, l_[2] = {0.f, 0.f};

#define STAGE_K(buf, l0)                                                        \
  do {                                                                          \
    _Pragma("unroll") for (int c = 0; c < 4; ++c) {                             \
      int row = w * 16 + c * 4 + (lane >> 4);                                   \
      gload_lds16(Kp + (size_t)((l0) + row) * HD + ((lane & 15) ^ (row & 15)) * 8, \
                  &Kl[buf][w * 16 + c * 4][0]);                                 \
    }                                                                           \
  } while (0)
#define STAGE_V(buf, l0)                                                        \
  do {                                                                          \
    _Pragma("unroll") for (int c = 0; c < 4; ++c) {                             \
      int d = w * 16 + c * 4 + (lane >> 4);                                     \
      gload_lds16(Vp + (size_t)d * LT + (l0) + ((lane & 15) ^ (d & 15)) * 8,    \
                  &Vl[buf][w * 16 + c * 4][0]);                                 \
    }                                                                           \
  } while (0)

  STAGE_K(0, 0);
  STAGE_V(0, 0);
  __syncthreads();

  for (int tt = 0; tt < NTT; ++tt) {
    const int cur = tt & 1;
    if (tt + 1 < NTT) {
      STAGE_K(cur ^ 1, (tt + 1) * KVB);
      STAGE_V(cur ^ 1, (tt + 1) * KVB);
    }

    f32x4 sc[2][8];
#pragma unroll
    for (int f = 0; f < 2; ++f)
#pragma unroll
      for (int cf = 0; cf < 8; ++cf) sc[f][cf] = fz;
#pragma unroll
    for (int cf = 0; cf < 8; ++cf)
#pragma unroll
      for (int kd = 0; kd < 4; ++kd) {
        s16x8 kb =
            *(const s16x8*)&Kl[cur][cf * 16 + lrow][((kd * 4 + kgrp) ^ lrow) * 8];
#pragma unroll
        for (int f = 0; f < 2; ++f) sc[f][cf] = MFMA(kb, qf[f][kd], sc[f][cf]);
      }

    float mxv[2];
#pragma unroll
    for (int f = 0; f < 2; ++f) {
      float mx = sc[f][0][0];
#pragma unroll
      for (int cf = 0; cf < 8; ++cf)
#pragma unroll
        for (int r = 0; r < 4; ++r) mx = fmaxf(mx, sc[f][cf][r]);
      mx *= SCALE2;
      mx = fmaxf(mx, __shfl_xor(mx, 16, 64));
      mx = fmaxf(mx, __shfl_xor(mx, 32, 64));
      mxv[f] = mx;
    }
    bool nb = (mxv[0] > m_[0] + 8.f) || (mxv[1] > m_[1] + 8.f);
    if (__any(nb)) {
#pragma unroll
      for (int f = 0; f < 2; ++f) {
        float mn = fmaxf(m_[f], mxv[f]);
        float so = exp2f(m_[f] - mn);
        m_[f] = mn;
        l_[f] *= so;
        float sob[4];
#pragma unroll
        for (int r = 0; r < 4; ++r) sob[r] = __shfl(so, kgrp * 4 + r, 16);
#pragma unroll
        for (int nd = 0; nd < 8; ++nd)
#pragma unroll
          for (int r = 0; r < 4; ++r) acc[f][nd][r] *= sob[r];
      }
    }

    float lp[2] = {0.f, 0.f};
#pragma unroll
    for (int half = 0; half < 2; ++half) {
      s16x8 pa[2][2];
#pragma unroll
      for (int f = 0; f < 2; ++f) {
#pragma unroll
        for (int cf = 0; cf < 4; ++cf) {
          int cfs = half * 4 + cf;
          bf16 pk[4];
#pragma unroll
          for (int r = 0; r < 4; ++r) {
            float p = exp2f(sc[f][cfs][r] * SCALE2 - m_[f]);
            lp[f] += p;
            pk[r] = __float2bfloat16(p);
          }
          __builtin_memcpy((void*)&P_lds[w][lrow][cf * 16 + kgrp * 4], pk, 8);
        }
#pragma unroll
        for (int kc = 0; kc < 2; ++kc)
          pa[f][kc] = *(const s16x8*)&P_lds[w][lrow][kc * 32 + kgrp * 8];
      }
#pragma unroll
      for (int nd = 0; nd < 8; ++nd)
#pragma unroll
        for (int kc = 0; kc < 2; ++kc) {
          s16x8 vb = *(const s16x8*)&Vl[cur][nd * 16 + lrow]
                                       [((half * 8 + kc * 4 + kgrp) ^ lrow) * 8];
#pragma unroll
          for (int f = 0; f < 2; ++f) acc[f][nd] = MFMA(pa[f][kc], vb, acc[f][nd]);
        }
    }
#pragma unroll
    for (int f = 0; f < 2; ++f) l_[f] += lp[f];

    __syncthreads();  // drains K/V(t+1) DMA; protects cur bufs for next stage
  }
#undef STAGE_K
#undef STAGE_V

  float li[2][4];
#pragma unroll
  for (int f = 0; f < 2; ++f) {
    float lv = l_[f];
    lv += __shfl_xor(lv, 16, 64);
    lv += __shfl_xor(lv, 32, 64);
#pragma unroll
    for (int r = 0; r < 4; ++r) li[f][r] = 1.f / __shfl(lv, kgrp * 4 + r, 16);
  }
#pragma unroll
  for (int f = 0; f < 2; ++f)
#pragma unroll
    for (int nd = 0; nd < 8; ++nd)
#pragma unroll
      for (int r = 0; r < 4; ++r) {
        int row = qb * 256 + w * 32 + f * 16 + kgrp * 4 + r;
        O[((size_t)b * SS + row) * 2048 + h * HD + nd * 16 + lrow] =
            __float2bfloat16(acc[f][nd][r] * li[f][r]);
      }
}

// ---------------- launch ----------------

extern "C" void kernel_launch(void* const* d_in, const int* in_sizes, int n_in,
                              void* d_out, int out_size, void* d_ws, size_t ws_size,
                              hipStream_t stream) {
  const float* hs = (const float*)d_in[0];
  const float* Wqkv = (const float*)d_in[1];
  const float* Wo = (const float*)d_in[2];
  const float* ctx_k = (const float*)d_in[3];
  const float* ctx_v = (const float*)d_in[4];
  const int* pid = (const int*)d_in[5];
  float* out = (float*)d_out;
  char* ws = (char*)d_ws;

  bf16* Hb = (bf16*)(ws);                      // 16.78 MB (reused as attn_out)
  bf16* WqT = (bf16*)(ws + 16777216);          // 16.78 MB
  bf16* WoT = (bf16*)(ws + 33554432);          // 8.39 MB
  bf16* qkv = (bf16*)(ws + 41943040);          // 33.55 MB (only Q half written)
  bf16* Kfull = (bf16*)(ws + 92274688);        // 25.17 MB
  bf16* Vt = (bf16*)(ws + 117440512);          // 25.17 MB
  float* cosT = (float*)(ws + 142606336);      // 256 KB
  float* sinT = (float*)(ws + 142606336 + 262144);
  bf16* attn = Hb;  // alias: Hb dead after QKV GEMM

  prep1<<<P1_RT, 512, 0, stream>>>(hs, Wqkv, pid, Hb, WqT, cosT, sinT);
  gemm_qkv<<<GQ_TOT, 512, 0, stream>>>(Hb, WqT, qkv, Kfull, Vt, cosT, sinT, Wo,
                                       WoT, ctx_k, ctx_v);
  flash_attn<<<256, 512, 0, stream>>>(qkv, cosT, sinT, Kfull, Vt, attn);
  gemm_bt<float><<<dim3(2048 / 128, MROWS / 256), 512, 0, stream>>>(
      attn, WoT, out, MROWS, 2048, HID);
}

// Round 19
// 303.635 us; speedup vs baseline: 1.0320x; 1.0320x over previous
//
#include <hip/hip_runtime.h>
#include <hip/hip_bf16.h>
#include <stdint.h>

#define NH 16
#define NKV 8
#define HD 128
#define BB 4
#define SS 1024
#define CTXL 2048
#define LT 3072
#define HID 2048
#define QKVN 4096
#define MROWS 4096

typedef __hip_bfloat16 bf16;
using f32x4 = __attribute__((ext_vector_type(4))) float;
using s16x8 = __attribute__((ext_vector_type(8))) short;

#define MFMA(a, b, c) __builtin_amdgcn_mfma_f32_16x16x32_bf16((a), (b), (c), 0, 0, 0)

__device__ __forceinline__ void gload_lds16(const void* g, void* l) {
  __builtin_amdgcn_global_load_lds((const __attribute__((address_space(1))) void*)g,
                                   (__attribute__((address_space(3))) void*)l, 16, 0, 0);
}

__device__ __forceinline__ void store_bf8(bf16* dst, const float* f) {
  bf16 tmp[8];
#pragma unroll
  for (int j = 0; j < 8; ++j) tmp[j] = __float2bfloat16(f[j]);
  __builtin_memcpy((void*)dst, (const void*)tmp, 16);
}

__device__ __forceinline__ float bf2f(short x) {
  unsigned int u = ((unsigned int)(unsigned short)x) << 16;
  float f;
  __builtin_memcpy(&f, &u, 4);
  return f;
}

// ---------------- prep1: cvt + weight transposes + rope table + ctx K/V ----
#define P1_CVT 4096
#define P1_WQ (P1_CVT + 8192)
#define P1_WO (P1_WQ + 4096)
#define P1_RT (P1_WO + 256)
#define P1_CK (P1_RT + 4096)
#define P1_CV (P1_CK + 8192)

__global__ void prep1(const float* __restrict__ hs, const float* __restrict__ Wqkv,
                      const float* __restrict__ Wo, const float* __restrict__ ck,
                      const float* __restrict__ cv, const int* __restrict__ pid,
                      bf16* __restrict__ Hb, bf16* __restrict__ WqT,
                      bf16* __restrict__ WoT, bf16* __restrict__ Kf,
                      bf16* __restrict__ Vt, float* __restrict__ cosT,
                      float* __restrict__ sinT) {
  __shared__ float tile[32][33];
  const int blk = blockIdx.x, thr = threadIdx.x;
  if (blk < P1_CVT) {
    size_t tid = (size_t)blk * 256 + thr;
    const float4* p = (const float4*)(hs + tid * 8);
    float4 a = p[0], b = p[1];
    float f[8] = {a.x, a.y, a.z, a.w, b.x, b.y, b.z, b.w};
    store_bf8(Hb + tid * 8, f);
  } else if (blk < P1_WQ) {
    int j = blk - P1_CVT;
    int c0 = (j & 127) * 32, r0 = (j >> 7) * 32;  // R=2048 C=4096
    int tx = thr & 31, ty = thr >> 5;
#pragma unroll
    for (int i = 0; i < 32; i += 8)
      tile[ty + i][tx] = Wqkv[(size_t)(r0 + ty + i) * QKVN + c0 + tx];
    __syncthreads();
#pragma unroll
    for (int i = 0; i < 32; i += 8)
      WqT[(size_t)(c0 + ty + i) * HID + r0 + tx] = __float2bfloat16(tile[tx][ty + i]);
  } else if (blk < P1_WO) {
    int j = blk - P1_WQ;
    int c0 = (j & 63) * 32, r0 = (j >> 6) * 32;  // 2048x2048
    int tx = thr & 31, ty = thr >> 5;
#pragma unroll
    for (int i = 0; i < 32; i += 8)
      tile[ty + i][tx] = Wo[(size_t)(r0 + ty + i) * 2048 + c0 + tx];
    __syncthreads();
#pragma unroll
    for (int i = 0; i < 32; i += 8)
      WoT[(size_t)(c0 + ty + i) * 2048 + r0 + tx] = __float2bfloat16(tile[tx][ty + i]);
  } else if (blk < P1_RT) {
    int tid = (blk - P1_WO) * 256 + thr;  // S*64
    int j = tid & 63, s = tid >> 6;
    int sec = (j < 8) ? 0 : (j < 16) ? 1 : (j < 40) ? 2 : 3;
    float pos = (float)pid[sec * SS + s];
    float inv = __expf(-(float)j * 0.14391156831212787f);  // ln(10000)/64
    float a = pos * inv;
    cosT[tid] = cosf(a);
    sinT[tid] = sinf(a);
  } else if (blk < P1_CK) {
    int tid = (blk - P1_RT) * 256 + thr;
    int d8 = tid & 15, l = (tid >> 4) & 2047, h = (tid >> 15) & 7, b = tid >> 18;
    const float* s = ck + (((size_t)b * CTXL + l) * NKV + h) * HD + d8 * 8;
    const float4* p = (const float4*)s;
    float4 a = p[0], bb = p[1];
    float f[8] = {a.x, a.y, a.z, a.w, bb.x, bb.y, bb.z, bb.w};
    store_bf8(Kf + (((size_t)(b * NKV + h)) * LT + l) * HD + d8 * 8, f);
  } else {
    int j = blk - P1_CK;
    int l0 = (j & 63) * 32, d0 = ((j >> 6) & 3) * 32;
    int bz = j >> 8, b = bz >> 3, h = bz & 7;
    int tx = thr & 31, ty = thr >> 5;
#pragma unroll
    for (int i = 0; i < 32; i += 8)
      tile[ty + i][tx] =
          cv[(((size_t)b * CTXL + l0 + ty + i) * NKV + h) * HD + d0 + tx];
    __syncthreads();
#pragma unroll
    for (int i = 0; i < 32; i += 8)
      Vt[(((size_t)(b * NKV + h)) * HD + d0 + ty + i) * LT + l0 + tx] =
          __float2bfloat16(tile[tx][ty + i]);
  }
}

// ---------------- QKV GEMM: 256x256 tile, 4-phase/K-tile interleave --------
__global__ __launch_bounds__(512, 1) void gemm_qkv(
    const bf16* __restrict__ A, const bf16* __restrict__ BT,
    bf16* __restrict__ qkv, bf16* __restrict__ Kf, bf16* __restrict__ Vt,
    const float* __restrict__ cosT, const float* __restrict__ sinT) {
  __shared__ __attribute__((aligned(16))) char smem[132096];
  bf16* lds = (bf16*)smem;
#define lAp(s, hf) (lds + ((s)*2 + (hf)) * 8192)
#define lBp(s, hf) (lds + 32768 + ((s)*2 + (hf)) * 8192)
  const int K = HID;
  const int t = threadIdx.x;
  const int lane = t & 63, w = t >> 6;
  const int wr = w >> 2, wc = w & 3;  // 2M x 4N
  const int lrow = lane & 15, kgrp = lane >> 4;
  const int lin = blockIdx.y * gridDim.x + blockIdx.x;
  const int qq = (gridDim.x * gridDim.y) >> 3;
  const int swz = (lin & 7) * qq + (lin >> 3);
  const int bx = swz % gridDim.x, by = swz / gridDim.x;
  const int m0 = by * 256, n0 = bx * 256;
  const f32x4 fz = {0.f, 0.f, 0.f, 0.f};
  f32x4 acc[8][4];
#pragma unroll
  for (int i = 0; i < 8; ++i)
#pragma unroll
    for (int j = 0; j < 4; ++j) acc[i][j] = fz;

#define STAGEH(sslot, skt, isB, shalf)                                        \
  do {                                                                        \
    _Pragma("unroll") for (int c = 0; c < 2; ++c) {                           \
      int row = w * 16 + c * 8 + (lane >> 3);                                 \
      int sch = (lane & 7) ^ (lane >> 3);                                     \
      const bf16* src =                                                       \
          (isB) ? (BT + (size_t)(n0 + (shalf)*128 + row) * K + (skt)*64 + sch * 8) \
                : (A + (size_t)(m0 + (shalf)*128 + row) * K + (skt)*64 + sch * 8); \
      bf16* dst = ((isB) ? lBp((sslot), (shalf)) : lAp((sslot), (shalf))) +   \
                  (w * 16 + c * 8) * 64;                                      \
      gload_lds16(src, dst);                                                  \
    }                                                                         \
  } while (0)

#define PHASE(cslot, qm, qn, DOST, sslot, skt, isB, shalf)                    \
  do {                                                                        \
    if (DOST) {                                                               \
      STAGEH(sslot, skt, isB, shalf);                                         \
      asm volatile("s_waitcnt vmcnt(2)" ::: "memory");                        \
    } else {                                                                  \
      asm volatile("s_waitcnt vmcnt(0)" ::: "memory");                        \
    }                                                                         \
    __builtin_amdgcn_s_barrier();                                             \
    __builtin_amdgcn_sched_barrier(0);                                        \
    s16x8 af_[4][2], bf_[2][2];                                               \
    _Pragma("unroll") for (int fi = 0; fi < 4; ++fi)                          \
        _Pragma("unroll") for (int ks = 0; ks < 2; ++ks) {                    \
      int row = (qm)*64 + fi * 16 + lrow;                                     \
      af_[fi][ks] = *(const s16x8*)&lAp(cslot, wr)[row * 64 +                 \
                                                   ((ks * 4 + kgrp) ^ (lrow & 7)) * 8]; \
    }                                                                         \
    _Pragma("unroll") for (int fj = 0; fj < 2; ++fj)                          \
        _Pragma("unroll") for (int ks = 0; ks < 2; ++ks) {                    \
      int col = (wc & 1) * 64 + (qn)*32 + fj * 16 + lrow;                     \
      bf_[fj][ks] = *(const s16x8*)&lBp(cslot, wc >> 1)[col * 64 +            \
                                                        ((ks * 4 + kgrp) ^ (lrow & 7)) * 8]; \
    }                                                                         \
    asm volatile("s_waitcnt lgkmcnt(0)" ::: "memory");                        \
    __builtin_amdgcn_sched_barrier(0);                                        \
    __builtin_amdgcn_s_setprio(1);                                            \
    _Pragma("unroll") for (int fi = 0; fi < 4; ++fi)                          \
        _Pragma("unroll") for (int fj = 0; fj < 2; ++fj)                      \
            _Pragma("unroll") for (int ks = 0; ks < 2; ++ks)                  \
                acc[(qm)*4 + fi][(qn)*2 + fj] =                               \
        MFMA(af_[fi][ks], bf_[fj][ks], acc[(qm)*4 + fi][(qn)*2 + fj]);        \
    __builtin_amdgcn_s_setprio(0);                                            \
    __builtin_amdgcn_s_barrier();                                             \
  } while (0)

  STAGEH(0, 0, 0, 0);
  STAGEH(0, 0, 1, 0);
  STAGEH(0, 0, 0, 1);
  STAGEH(0, 0, 1, 1);
  asm volatile("s_waitcnt vmcnt(0)" ::: "memory");
  __builtin_amdgcn_s_barrier();

  for (int kt = 0; kt < 32; kt += 2) {
    PHASE(0, 0, 0, true, 1, kt + 1, 0, 0);
    PHASE(0, 1, 0, true, 1, kt + 1, 1, 0);
    PHASE(0, 0, 1, true, 1, kt + 1, 0, 1);
    PHASE(0, 1, 1, true, 1, kt + 1, 1, 1);
    const bool d2 = (kt + 2 < 32);
    PHASE(1, 0, 0, d2, 0, kt + 2, 0, 0);
    PHASE(1, 1, 0, d2, 0, kt + 2, 1, 0);
    PHASE(1, 0, 1, d2, 0, kt + 2, 0, 1);
    PHASE(1, 1, 1, d2, 0, kt + 2, 1, 1);
  }
#undef PHASE
#undef STAGEH

  const int b = m0 >> 10, s0 = m0 & 1023;
  if (n0 < 2048) {
#pragma unroll
    for (int fm = 0; fm < 8; ++fm)
#pragma unroll
      for (int fn = 0; fn < 4; ++fn)
#pragma unroll
        for (int r = 0; r < 4; ++r) {
          int row = m0 + wr * 128 + fm * 16 + kgrp * 4 + r;
          int col = n0 + wc * 64 + fn * 16 + lrow;
          qkv[(size_t)row * QKVN + col] = __float2bfloat16(acc[fm][fn][r]);
        }
  } else {
    float* stage = (float*)smem;  // [256][129] f32 = 132096 B
#pragma unroll 1
    for (int hh = 0; hh < 2; ++hh) {
      __syncthreads();
      if ((wc >> 1) == hh) {
#pragma unroll
        for (int fm = 0; fm < 8; ++fm)
#pragma unroll
          for (int fn = 0; fn < 4; ++fn)
#pragma unroll
            for (int r = 0; r < 4; ++r) {
              int rr = wr * 128 + fm * 16 + kgrp * 4 + r;
              int cc = (wc & 1) * 64 + fn * 16 + lrow;
              stage[rr * 129 + cc] = acc[fm][fn][r];
            }
      }
      __syncthreads();
      if (n0 < 3072) {
        int h = ((n0 - 2048) >> 7) + hh;
#pragma unroll 4
        for (int it = 0; it < 32; ++it) {
          int idx = it * 512 + t;
          int r = idx >> 6, j = idx & 63;
          float x1 = stage[r * 129 + j], x2 = stage[r * 129 + j + 64];
          int s = s0 + r;
          float c = cosT[s * 64 + j], sn = sinT[s * 64 + j];
          bf16* dst = Kf + ((size_t)(b * NKV + h) * LT + CTXL + s) * HD;
          dst[j] = __float2bfloat16(x1 * c - x2 * sn);
          dst[j + 64] = __float2bfloat16(x2 * c + x1 * sn);
        }
      } else {
        int h = ((n0 - 3072) >> 7) + hh;
#pragma unroll 4
        for (int it = 0; it < 64; ++it) {
          int idx = it * 512 + t;
          int soff = idx & 255, d = idx >> 8;
          Vt[((size_t)(b * NKV + h) * HD + d) * LT + CTXL + s0 + soff] =
              __float2bfloat16(stage[soff * 129 + d]);
        }
      }
    }
  }
#undef lAp
#undef lBp
}

// ---------------- out-proj GEMM: 256x128 tile, 4-phase/K-tile --------------
// 8 waves 2M x 4N (wave tile 128x32), acc[8][2]. 2 LDS slots x (A 32K + B
// 16K) = 96 KB. 6 loads/thread/K-tile staged {A0,A1,B} across phases 1-3;
// counted vmcnt(2/4/6/6) certifies the consuming tile landed (loads complete
// in issue order). XOR chunk swizzle both sides (rule 21). f32 output.
__global__ __launch_bounds__(512, 1) void gemm_op(const bf16* __restrict__ A,
                                                  const bf16* __restrict__ BT,
                                                  float* __restrict__ C) {
  __shared__ __attribute__((aligned(16))) bf16 lA[2][256][64];  // 64 KB
  __shared__ __attribute__((aligned(16))) bf16 lB[2][128][64];  // 32 KB
  const int K = HID, N = 2048;
  const int t = threadIdx.x;
  const int lane = t & 63, w = t >> 6;
  const int wr = w >> 2, wc = w & 3;  // 2M x 4N
  const int lrow = lane & 15, kgrp = lane >> 4;
  const int lin = blockIdx.y * gridDim.x + blockIdx.x;
  const int qq = (gridDim.x * gridDim.y) >> 3;
  const int swz = (lin & 7) * qq + (lin >> 3);
  const int bx = swz % gridDim.x, by = swz / gridDim.x;
  const int m0 = by * 256, n0 = bx * 128;
  const f32x4 fz = {0.f, 0.f, 0.f, 0.f};
  f32x4 acc[8][2];
#pragma unroll
  for (int i = 0; i < 8; ++i)
#pragma unroll
    for (int j = 0; j < 2; ++j) acc[i][j] = fz;

#define OSA(sslot, skt, half)                                                 \
  do {                                                                        \
    _Pragma("unroll") for (int c = 0; c < 2; ++c) {                           \
      int row = w * 16 + c * 8 + (lane >> 3);                                 \
      int sch = (lane & 7) ^ (lane >> 3);                                     \
      gload_lds16(A + (size_t)(m0 + (half)*128 + row) * K + (skt)*64 + sch * 8, \
                  &lA[sslot][(half)*128 + w * 16 + c * 8][0]);                \
    }                                                                         \
  } while (0)
#define OSB(sslot, skt)                                                       \
  do {                                                                        \
    _Pragma("unroll") for (int c = 0; c < 2; ++c) {                           \
      int row = w * 16 + c * 8 + (lane >> 3);                                 \
      int sch = (lane & 7) ^ (lane >> 3);                                     \
      gload_lds16(BT + (size_t)(n0 + row) * K + (skt)*64 + sch * 8,           \
                  &lB[sslot][w * 16 + c * 8][0]);                             \
    }                                                                         \
  } while (0)

#define OPHASE(cslot, qm, qn, DOST, STG, VMC)                                 \
  do {                                                                        \
    if (DOST) {                                                               \
      STG;                                                                    \
      asm volatile("s_waitcnt vmcnt(" #VMC ")" ::: "memory");                 \
    } else {                                                                  \
      asm volatile("s_waitcnt vmcnt(0)" ::: "memory");                        \
    }                                                                         \
    __builtin_amdgcn_s_barrier();                                             \
    __builtin_amdgcn_sched_barrier(0);                                        \
    s16x8 af_[4][2], bf_[2];                                                  \
    _Pragma("unroll") for (int fi = 0; fi < 4; ++fi)                          \
        _Pragma("unroll") for (int ks = 0; ks < 2; ++ks) {                    \
      int row = wr * 128 + (qm)*64 + fi * 16 + lrow;                          \
      af_[fi][ks] = *(const s16x8*)&lA[cslot][row]                            \
                                       [((ks * 4 + kgrp) ^ (lrow & 7)) * 8];  \
    }                                                                         \
    _Pragma("unroll") for (int ks = 0; ks < 2; ++ks) {                        \
      int col = wc * 32 + (qn)*16 + lrow;                                     \
      bf_[ks] = *(const s16x8*)&lB[cslot][col]                                \
                                   [((ks * 4 + kgrp) ^ (lrow & 7)) * 8];      \
    }                                                                         \
    asm volatile("s_waitcnt lgkmcnt(0)" ::: "memory");                        \
    __builtin_amdgcn_sched_barrier(0);                                        \
    __builtin_amdgcn_s_setprio(1);                                            \
    _Pragma("unroll") for (int fi = 0; fi < 4; ++fi)                          \
        _Pragma("unroll") for (int ks = 0; ks < 2; ++ks)                      \
            acc[(qm)*4 + fi][qn] =                                            \
        MFMA(af_[fi][ks], bf_[ks], acc[(qm)*4 + fi][qn]);                     \
    __builtin_amdgcn_s_setprio(0);                                            \
    __builtin_amdgcn_s_barrier();                                             \
  } while (0)

  // prologue: tile 0 -> slot 0, full drain
  OSA(0, 0, 0);
  OSA(0, 0, 1);
  OSB(0, 0);
  asm volatile("s_waitcnt vmcnt(0)" ::: "memory");
  __builtin_amdgcn_s_barrier();

  for (int kt = 0; kt < 32; kt += 2) {
    // tile kt (slot 0); stage kt+1 -> slot 1
    OPHASE(0, 0, 0, true, OSA(1, kt + 1, 0), 2);
    OPHASE(0, 1, 0, true, OSA(1, kt + 1, 1), 4);
    OPHASE(0, 0, 1, true, OSB(1, kt + 1), 6);
    OPHASE(0, 1, 1, false, (void)0, 6);
    // tile kt+1 (slot 1); stage kt+2 -> slot 0 (if exists)
    const bool d2 = (kt + 2 < 32);
    OPHASE(1, 0, 0, d2, OSA(0, kt + 2, 0), 2);
    OPHASE(1, 1, 0, d2, OSA(0, kt + 2, 1), 4);
    OPHASE(1, 0, 1, d2, OSB(0, kt + 2), 6);
    OPHASE(1, 1, 1, false, (void)0, 6);
  }
#undef OPHASE
#undef OSA
#undef OSB

#pragma unroll
  for (int fm = 0; fm < 8; ++fm)
#pragma unroll
    for (int fn = 0; fn < 2; ++fn)
#pragma unroll
      for (int r = 0; r < 4; ++r) {
        int row = m0 + wr * 128 + fm * 16 + kgrp * 4 + r;
        int col = n0 + wc * 32 + fn * 16 + lrow;
        C[(size_t)row * N + col] = acc[fm][fn][r];
      }
}

// ---------------- flash attention (KVBLK=128, K+V double-buffered) --------
#define PSTR 72  // P row stride in elements: 144B = 16B-aligned
#define KVB 128
#define NTT 24   // LT / 128
#define SCALE2 0.1275174335919605f  // scale * log2(e)

__global__ __launch_bounds__(512, 2) void flash_attn(
    const bf16* __restrict__ qkv, const float* __restrict__ cosT,
    const float* __restrict__ sinT, const bf16* __restrict__ Kf,
    const bf16* __restrict__ Vt, bf16* __restrict__ O) {
  __shared__ __attribute__((aligned(16))) bf16 Kl[2][128][128];     // 64 KB
  __shared__ __attribute__((aligned(16))) bf16 Vl[2][128][128];     // 64 KB
  __shared__ __attribute__((aligned(16))) bf16 P_lds[8][16][PSTR];  // 18 KB
  const int t = threadIdx.x, lane = t & 63, w = t >> 6;
  // XCD panel swizzle (bijective): b=id>>6, hk=id&7, h=(hk<<1)|bit5, qb=bits3-4
  const int id = blockIdx.x;
  const int b = id >> 6, hk = id & 7;
  const int h = (hk << 1) | ((id >> 5) & 1);
  const int qb = (id >> 3) & 3;
  const int lrow = lane & 15, kgrp = lane >> 4;
  const bf16* Kp = Kf + (size_t)(b * NKV + hk) * LT * HD;
  const bf16* Vp = Vt + (size_t)(b * NKV + hk) * HD * LT;

  // prologue: load Q rows from qkv and apply RoPE in-register
  s16x8 qf[2][4];
#pragma unroll
  for (int f = 0; f < 2; ++f) {
    int srw_i = qb * 256 + w * 32 + f * 16 + lrow;
    const bf16* qrow = qkv + ((size_t)b * SS + srw_i) * QKVN + h * HD;
    s16x8 qr[4];
#pragma unroll
    for (int kd = 0; kd < 4; ++kd)
      qr[kd] = *(const s16x8*)&qrow[kd * 32 + kgrp * 8];
    const float* crow = cosT + srw_i * 64 + kgrp * 8;
    const float* srow = sinT + srw_i * 64 + kgrp * 8;
    float qv[4][8], cc[2][8], ssv[2][8];
#pragma unroll
    for (int kd = 0; kd < 4; ++kd)
#pragma unroll
      for (int j = 0; j < 8; ++j) qv[kd][j] = bf2f(qr[kd][j]);
#pragma unroll
    for (int g = 0; g < 2; ++g)
#pragma unroll
      for (int j = 0; j < 8; ++j) {
        cc[g][j] = crow[g * 32 + j];
        ssv[g][j] = srow[g * 32 + j];
      }
    bf16 o[4][8];
#pragma unroll
    for (int j = 0; j < 8; ++j) {
      o[0][j] = __float2bfloat16(qv[0][j] * cc[0][j] - qv[2][j] * ssv[0][j]);
      o[1][j] = __float2bfloat16(qv[1][j] * cc[1][j] - qv[3][j] * ssv[1][j]);
      o[2][j] = __float2bfloat16(qv[2][j] * cc[0][j] + qv[0][j] * ssv[0][j]);
      o[3][j] = __float2bfloat16(qv[3][j] * cc[1][j] + qv[1][j] * ssv[1][j]);
    }
#pragma unroll
    for (int kd = 0; kd < 4; ++kd) __builtin_memcpy(&qf[f][kd], o[kd], 16);
  }

  const f32x4 fz = {0.f, 0.f, 0.f, 0.f};
  f32x4 acc[2][8];
#pragma unroll
  for (int f = 0; f < 2; ++f)
#pragma unroll
    for (int i = 0; i < 8; ++i) acc[f][i] = fz;
  float m_[2] = {-1e30f, -1e30f}, l_[2] = {0.f, 0.f};

#define STAGE_K(buf, l0)                                                        \
  do {                                                                          \
    _Pragma("unroll") for (int c = 0; c < 4; ++c) {                             \
      int row = w * 16 + c * 4 + (lane >> 4);                                   \
      gload_lds16(Kp + (size_t)((l0) + row) * HD + ((lane & 15) ^ (row & 15)) * 8, \
                  &Kl[buf][w * 16 + c * 4][0]);                                 \
    }                                                                           \
  } while (0)
#define STAGE_V(buf, l0)                                                        \
  do {                                                                          \
    _Pragma("unroll") for (int c = 0; c < 4; ++c) {                             \
      int d = w * 16 + c * 4 + (lane >> 4);                                     \
      gload_lds16(Vp + (size_t)d * LT + (l0) + ((lane & 15) ^ (d & 15)) * 8,    \
                  &Vl[buf][w * 16 + c * 4][0]);                                 \
    }                                                                           \
  } while (0)

  STAGE_K(0, 0);
  STAGE_V(0, 0);
  __syncthreads();

  for (int tt = 0; tt < NTT; ++tt) {
    const int cur = tt & 1;
    if (tt + 1 < NTT) {
      STAGE_K(cur ^ 1, (tt + 1) * KVB);
      STAGE_V(cur ^ 1, (tt + 1) * KVB);
    }

    f32x4 sc[2][8];
#pragma unroll
    for (int f = 0; f < 2; ++f)
#pragma unroll
      for (int cf = 0; cf < 8; ++cf) sc[f][cf] = fz;
#pragma unroll
    for (int cf = 0; cf < 8; ++cf)
#pragma unroll
      for (int kd = 0; kd < 4; ++kd) {
        s16x8 kb =
            *(const s16x8*)&Kl[cur][cf * 16 + lrow][((kd * 4 + kgrp) ^ lrow) * 8];
#pragma unroll
        for (int f = 0; f < 2; ++f) sc[f][cf] = MFMA(kb, qf[f][kd], sc[f][cf]);
      }

    float mxv[2];
#pragma unroll
    for (int f = 0; f < 2; ++f) {
      float mx = sc[f][0][0];
#pragma unroll
      for (int cf = 0; cf < 8; ++cf)
#pragma unroll
        for (int r = 0; r < 4; ++r) mx = fmaxf(mx, sc[f][cf][r]);
      mx *= SCALE2;
      mx = fmaxf(mx, __shfl_xor(mx, 16, 64));
      mx = fmaxf(mx, __shfl_xor(mx, 32, 64));
      mxv[f] = mx;
    }
    bool nb = (mxv[0] > m_[0] + 8.f) || (mxv[1] > m_[1] + 8.f);
    if (__any(nb)) {
#pragma unroll
      for (int f = 0; f < 2; ++f) {
        float mn = fmaxf(m_[f], mxv[f]);
        float so = exp2f(m_[f] - mn);
        m_[f] = mn;
        l_[f] *= so;
        float sob[4];
#pragma unroll
        for (int r = 0; r < 4; ++r) sob[r] = __shfl(so, kgrp * 4 + r, 16);
#pragma unroll
        for (int nd = 0; nd < 8; ++nd)
#pragma unroll
          for (int r = 0; r < 4; ++r) acc[f][nd][r] *= sob[r];
      }
    }

    float lp[2] = {0.f, 0.f};
#pragma unroll
    for (int half = 0; half < 2; ++half) {
      s16x8 pa[2][2];
#pragma unroll
      for (int f = 0; f < 2; ++f) {
#pragma unroll
        for (int cf = 0; cf < 4; ++cf) {
          int cfs = half * 4 + cf;
          bf16 pk[4];
#pragma unroll
          for (int r = 0; r < 4; ++r) {
            float p = exp2f(sc[f][cfs][r] * SCALE2 - m_[f]);
            lp[f] += p;
            pk[r] = __float2bfloat16(p);
          }
          __builtin_memcpy((void*)&P_lds[w][lrow][cf * 16 + kgrp * 4], pk, 8);
        }
#pragma unroll
        for (int kc = 0; kc < 2; ++kc)
          pa[f][kc] = *(const s16x8*)&P_lds[w][lrow][kc * 32 + kgrp * 8];
      }
#pragma unroll
      for (int nd = 0; nd < 8; ++nd)
#pragma unroll
        for (int kc = 0; kc < 2; ++kc) {
          s16x8 vb = *(const s16x8*)&Vl[cur][nd * 16 + lrow]
                                       [((half * 8 + kc * 4 + kgrp) ^ lrow) * 8];
#pragma unroll
          for (int f = 0; f < 2; ++f) acc[f][nd] = MFMA(pa[f][kc], vb, acc[f][nd]);
        }
    }
#pragma unroll
    for (int f = 0; f < 2; ++f) l_[f] += lp[f];

    __syncthreads();  // drains K/V(t+1) DMA; protects cur bufs for next stage
  }
#undef STAGE_K
#undef STAGE_V

  float li[2][4];
#pragma unroll
  for (int f = 0; f < 2; ++f) {
    float lv = l_[f];
    lv += __shfl_xor(lv, 16, 64);
    lv += __shfl_xor(lv, 32, 64);
#pragma unroll
    for (int r = 0; r < 4; ++r) li[f][r] = 1.f / __shfl(lv, kgrp * 4 + r, 16);
  }
#pragma unroll
  for (int f = 0; f < 2; ++f)
#pragma unroll
    for (int nd = 0; nd < 8; ++nd)
#pragma unroll
      for (int r = 0; r < 4; ++r) {
        int row = qb * 256 + w * 32 + f * 16 + kgrp * 4 + r;
        O[((size_t)b * SS + row) * 2048 + h * HD + nd * 16 + lrow] =
            __float2bfloat16(acc[f][nd][r] * li[f][r]);
      }
}

// ---------------- launch ----------------

extern "C" void kernel_launch(void* const* d_in, const int* in_sizes, int n_in,
                              void* d_out, int out_size, void* d_ws, size_t ws_size,
                              hipStream_t stream) {
  const float* hs = (const float*)d_in[0];
  const float* Wqkv = (const float*)d_in[1];
  const float* Wo = (const float*)d_in[2];
  const float* ctx_k = (const float*)d_in[3];
  const float* ctx_v = (const float*)d_in[4];
  const int* pid = (const int*)d_in[5];
  float* out = (float*)d_out;
  char* ws = (char*)d_ws;

  bf16* Hb = (bf16*)(ws);                      // 16.78 MB (reused as attn_out)
  bf16* WqT = (bf16*)(ws + 16777216);          // 16.78 MB
  bf16* WoT = (bf16*)(ws + 33554432);          // 8.39 MB
  bf16* qkv = (bf16*)(ws + 41943040);          // 33.55 MB (only Q half written)
  bf16* Kfull = (bf16*)(ws + 92274688);        // 25.17 MB
  bf16* Vt = (bf16*)(ws + 117440512);          // 25.17 MB
  float* cosT = (float*)(ws + 142606336);      // 256 KB
  float* sinT = (float*)(ws + 142606336 + 262144);
  bf16* attn = Hb;  // alias: Hb dead after QKV GEMM

  prep1<<<P1_CV, 256, 0, stream>>>(hs, Wqkv, Wo, ctx_k, ctx_v, pid, Hb, WqT, WoT,
                                   Kfull, Vt, cosT, sinT);
  gemm_qkv<<<dim3(QKVN / 256, MROWS / 256), 512, 0, stream>>>(
      Hb, WqT, qkv, Kfull, Vt, cosT, sinT);
  flash_attn<<<256, 512, 0, stream>>>(qkv, cosT, sinT, Kfull, Vt, attn);
  gemm_op<<<dim3(2048 / 128, MROWS / 256), 512, 0, stream>>>(attn, WoT, out);
}

// Round 20
// 291.666 us; speedup vs baseline: 1.0744x; 1.0410x over previous
//
#include <hip/hip_runtime.h>
#include <hip/hip_bf16.h>
#include <stdint.h>

#define NH 16
#define NKV 8
#define HD 128
#define BB 4
#define SS 1024
#define CTXL 2048
#define LT 3072
#define HID 2048
#define QKVN 4096
#define MROWS 4096

typedef __hip_bfloat16 bf16;
using f32x4 = __attribute__((ext_vector_type(4))) float;
using s16x8 = __attribute__((ext_vector_type(8))) short;

#define MFMA(a, b, c) __builtin_amdgcn_mfma_f32_16x16x32_bf16((a), (b), (c), 0, 0, 0)

__device__ __forceinline__ void gload_lds16(const void* g, void* l) {
  __builtin_amdgcn_global_load_lds((const __attribute__((address_space(1))) void*)g,
                                   (__attribute__((address_space(3))) void*)l, 16, 0, 0);
}

__device__ __forceinline__ void store_bf8(bf16* dst, const float* f) {
  bf16 tmp[8];
#pragma unroll
  for (int j = 0; j < 8; ++j) tmp[j] = __float2bfloat16(f[j]);
  __builtin_memcpy((void*)dst, (const void*)tmp, 16);
}

__device__ __forceinline__ float bf2f(short x) {
  unsigned int u = ((unsigned int)(unsigned short)x) << 16;
  float f;
  __builtin_memcpy(&f, &u, 4);
  return f;
}

// ---------------- prep1: cvt + weight transposes + rope table + ctx K/V ----
#define P1_CVT 4096
#define P1_WQ (P1_CVT + 8192)
#define P1_WO (P1_WQ + 4096)
#define P1_RT (P1_WO + 256)
#define P1_CK (P1_RT + 4096)
#define P1_CV (P1_CK + 8192)

__global__ void prep1(const float* __restrict__ hs, const float* __restrict__ Wqkv,
                      const float* __restrict__ Wo, const float* __restrict__ ck,
                      const float* __restrict__ cv, const int* __restrict__ pid,
                      bf16* __restrict__ Hb, bf16* __restrict__ WqT,
                      bf16* __restrict__ WoT, bf16* __restrict__ Kf,
                      bf16* __restrict__ Vt, float* __restrict__ cosT,
                      float* __restrict__ sinT) {
  __shared__ float tile[32][33];
  const int blk = blockIdx.x, thr = threadIdx.x;
  if (blk < P1_CVT) {
    size_t tid = (size_t)blk * 256 + thr;
    const float4* p = (const float4*)(hs + tid * 8);
    float4 a = p[0], b = p[1];
    float f[8] = {a.x, a.y, a.z, a.w, b.x, b.y, b.z, b.w};
    store_bf8(Hb + tid * 8, f);
  } else if (blk < P1_WQ) {
    int j = blk - P1_CVT;
    int c0 = (j & 127) * 32, r0 = (j >> 7) * 32;  // R=2048 C=4096
    int tx = thr & 31, ty = thr >> 5;
#pragma unroll
    for (int i = 0; i < 32; i += 8)
      tile[ty + i][tx] = Wqkv[(size_t)(r0 + ty + i) * QKVN + c0 + tx];
    __syncthreads();
#pragma unroll
    for (int i = 0; i < 32; i += 8)
      WqT[(size_t)(c0 + ty + i) * HID + r0 + tx] = __float2bfloat16(tile[tx][ty + i]);
  } else if (blk < P1_WO) {
    int j = blk - P1_WQ;
    int c0 = (j & 63) * 32, r0 = (j >> 6) * 32;  // 2048x2048
    int tx = thr & 31, ty = thr >> 5;
#pragma unroll
    for (int i = 0; i < 32; i += 8)
      tile[ty + i][tx] = Wo[(size_t)(r0 + ty + i) * 2048 + c0 + tx];
    __syncthreads();
#pragma unroll
    for (int i = 0; i < 32; i += 8)
      WoT[(size_t)(c0 + ty + i) * 2048 + r0 + tx] = __float2bfloat16(tile[tx][ty + i]);
  } else if (blk < P1_RT) {
    int tid = (blk - P1_WO) * 256 + thr;  // S*64
    int j = tid & 63, s = tid >> 6;
    int sec = (j < 8) ? 0 : (j < 16) ? 1 : (j < 40) ? 2 : 3;
    float pos = (float)pid[sec * SS + s];
    float inv = __expf(-(float)j * 0.14391156831212787f);  // ln(10000)/64
    float a = pos * inv;
    cosT[tid] = cosf(a);
    sinT[tid] = sinf(a);
  } else if (blk < P1_CK) {
    int tid = (blk - P1_RT) * 256 + thr;
    int d8 = tid & 15, l = (tid >> 4) & 2047, h = (tid >> 15) & 7, b = tid >> 18;
    const float* s = ck + (((size_t)b * CTXL + l) * NKV + h) * HD + d8 * 8;
    const float4* p = (const float4*)s;
    float4 a = p[0], bb = p[1];
    float f[8] = {a.x, a.y, a.z, a.w, bb.x, bb.y, bb.z, bb.w};
    store_bf8(Kf + (((size_t)(b * NKV + h)) * LT + l) * HD + d8 * 8, f);
  } else {
    int j = blk - P1_CK;
    int l0 = (j & 63) * 32, d0 = ((j >> 6) & 3) * 32;
    int bz = j >> 8, b = bz >> 3, h = bz & 7;
    int tx = thr & 31, ty = thr >> 5;
#pragma unroll
    for (int i = 0; i < 32; i += 8)
      tile[ty + i][tx] =
          cv[(((size_t)b * CTXL + l0 + ty + i) * NKV + h) * HD + d0 + tx];
    __syncthreads();
#pragma unroll
    for (int i = 0; i < 32; i += 8)
      Vt[(((size_t)(b * NKV + h)) * HD + d0 + ty + i) * LT + l0 + tx] =
          __float2bfloat16(tile[tx][ty + i]);
  }
}

// ---------------- QKV GEMM: 256x256 tile, 4-phase/K-tile interleave --------
__global__ __launch_bounds__(512, 1) void gemm_qkv(
    const bf16* __restrict__ A, const bf16* __restrict__ BT,
    bf16* __restrict__ qkv, bf16* __restrict__ Kf, bf16* __restrict__ Vt,
    const float* __restrict__ cosT, const float* __restrict__ sinT) {
  __shared__ __attribute__((aligned(16))) char smem[132096];
  bf16* lds = (bf16*)smem;
#define lAp(s, hf) (lds + ((s)*2 + (hf)) * 8192)
#define lBp(s, hf) (lds + 32768 + ((s)*2 + (hf)) * 8192)
  const int K = HID;
  const int t = threadIdx.x;
  const int lane = t & 63, w = t >> 6;
  const int wr = w >> 2, wc = w & 3;  // 2M x 4N
  const int lrow = lane & 15, kgrp = lane >> 4;
  const int lin = blockIdx.y * gridDim.x + blockIdx.x;
  const int qq = (gridDim.x * gridDim.y) >> 3;
  const int swz = (lin & 7) * qq + (lin >> 3);
  const int bx = swz % gridDim.x, by = swz / gridDim.x;
  const int m0 = by * 256, n0 = bx * 256;
  const f32x4 fz = {0.f, 0.f, 0.f, 0.f};
  f32x4 acc[8][4];
#pragma unroll
  for (int i = 0; i < 8; ++i)
#pragma unroll
    for (int j = 0; j < 4; ++j) acc[i][j] = fz;

#define STAGEH(sslot, skt, isB, shalf)                                        \
  do {                                                                        \
    _Pragma("unroll") for (int c = 0; c < 2; ++c) {                           \
      int row = w * 16 + c * 8 + (lane >> 3);                                 \
      int sch = (lane & 7) ^ (lane >> 3);                                     \
      const bf16* src =                                                       \
          (isB) ? (BT + (size_t)(n0 + (shalf)*128 + row) * K + (skt)*64 + sch * 8) \
                : (A + (size_t)(m0 + (shalf)*128 + row) * K + (skt)*64 + sch * 8); \
      bf16* dst = ((isB) ? lBp((sslot), (shalf)) : lAp((sslot), (shalf))) +   \
                  (w * 16 + c * 8) * 64;                                      \
      gload_lds16(src, dst);                                                  \
    }                                                                         \
  } while (0)

#define PHASE(cslot, qm, qn, DOST, sslot, skt, isB, shalf)                    \
  do {                                                                        \
    if (DOST) {                                                               \
      STAGEH(sslot, skt, isB, shalf);                                         \
      asm volatile("s_waitcnt vmcnt(2)" ::: "memory");                        \
    } else {                                                                  \
      asm volatile("s_waitcnt vmcnt(0)" ::: "memory");                        \
    }                                                                         \
    __builtin_amdgcn_s_barrier();                                             \
    __builtin_amdgcn_sched_barrier(0);                                        \
    s16x8 af_[4][2], bf_[2][2];                                               \
    _Pragma("unroll") for (int fi = 0; fi < 4; ++fi)                          \
        _Pragma("unroll") for (int ks = 0; ks < 2; ++ks) {                    \
      int row = (qm)*64 + fi * 16 + lrow;                                     \
      af_[fi][ks] = *(const s16x8*)&lAp(cslot, wr)[row * 64 +                 \
                                                   ((ks * 4 + kgrp) ^ (lrow & 7)) * 8]; \
    }                                                                         \
    _Pragma("unroll") for (int fj = 0; fj < 2; ++fj)                          \
        _Pragma("unroll") for (int ks = 0; ks < 2; ++ks) {                    \
      int col = (wc & 1) * 64 + (qn)*32 + fj * 16 + lrow;                     \
      bf_[fj][ks] = *(const s16x8*)&lBp(cslot, wc >> 1)[col * 64 +            \
                                                        ((ks * 4 + kgrp) ^ (lrow & 7)) * 8]; \
    }                                                                         \
    asm volatile("s_waitcnt lgkmcnt(0)" ::: "memory");                        \
    __builtin_amdgcn_sched_barrier(0);                                        \
    __builtin_amdgcn_s_setprio(1);                                            \
    _Pragma("unroll") for (int fi = 0; fi < 4; ++fi)                          \
        _Pragma("unroll") for (int fj = 0; fj < 2; ++fj)                      \
            _Pragma("unroll") for (int ks = 0; ks < 2; ++ks)                  \
                acc[(qm)*4 + fi][(qn)*2 + fj] =                               \
        MFMA(af_[fi][ks], bf_[fj][ks], acc[(qm)*4 + fi][(qn)*2 + fj]);        \
    __builtin_amdgcn_s_setprio(0);                                            \
    __builtin_amdgcn_s_barrier();                                             \
  } while (0)

  STAGEH(0, 0, 0, 0);
  STAGEH(0, 0, 1, 0);
  STAGEH(0, 0, 0, 1);
  STAGEH(0, 0, 1, 1);
  asm volatile("s_waitcnt vmcnt(0)" ::: "memory");
  __builtin_amdgcn_s_barrier();

  for (int kt = 0; kt < 32; kt += 2) {
    PHASE(0, 0, 0, true, 1, kt + 1, 0, 0);
    PHASE(0, 1, 0, true, 1, kt + 1, 1, 0);
    PHASE(0, 0, 1, true, 1, kt + 1, 0, 1);
    PHASE(0, 1, 1, true, 1, kt + 1, 1, 1);
    const bool d2 = (kt + 2 < 32);
    PHASE(1, 0, 0, d2, 0, kt + 2, 0, 0);
    PHASE(1, 1, 0, d2, 0, kt + 2, 1, 0);
    PHASE(1, 0, 1, d2, 0, kt + 2, 0, 1);
    PHASE(1, 1, 1, d2, 0, kt + 2, 1, 1);
  }
#undef PHASE
#undef STAGEH

  const int b = m0 >> 10, s0 = m0 & 1023;
  if (n0 < 2048) {
#pragma unroll
    for (int fm = 0; fm < 8; ++fm)
#pragma unroll
      for (int fn = 0; fn < 4; ++fn)
#pragma unroll
        for (int r = 0; r < 4; ++r) {
          int row = m0 + wr * 128 + fm * 16 + kgrp * 4 + r;
          int col = n0 + wc * 64 + fn * 16 + lrow;
          qkv[(size_t)row * QKVN + col] = __float2bfloat16(acc[fm][fn][r]);
        }
  } else {
    float* stage = (float*)smem;  // [256][129] f32 = 132096 B
#pragma unroll 1
    for (int hh = 0; hh < 2; ++hh) {
      __syncthreads();
      if ((wc >> 1) == hh) {
#pragma unroll
        for (int fm = 0; fm < 8; ++fm)
#pragma unroll
          for (int fn = 0; fn < 4; ++fn)
#pragma unroll
            for (int r = 0; r < 4; ++r) {
              int rr = wr * 128 + fm * 16 + kgrp * 4 + r;
              int cc = (wc & 1) * 64 + fn * 16 + lrow;
              stage[rr * 129 + cc] = acc[fm][fn][r];
            }
      }
      __syncthreads();
      if (n0 < 3072) {
        int h = ((n0 - 2048) >> 7) + hh;
#pragma unroll 4
        for (int it = 0; it < 32; ++it) {
          int idx = it * 512 + t;
          int r = idx >> 6, j = idx & 63;
          float x1 = stage[r * 129 + j], x2 = stage[r * 129 + j + 64];
          int s = s0 + r;
          float c = cosT[s * 64 + j], sn = sinT[s * 64 + j];
          bf16* dst = Kf + ((size_t)(b * NKV + h) * LT + CTXL + s) * HD;
          dst[j] = __float2bfloat16(x1 * c - x2 * sn);
          dst[j + 64] = __float2bfloat16(x2 * c + x1 * sn);
        }
      } else {
        int h = ((n0 - 3072) >> 7) + hh;
#pragma unroll 4
        for (int it = 0; it < 64; ++it) {
          int idx = it * 512 + t;
          int soff = idx & 255, d = idx >> 8;
          Vt[((size_t)(b * NKV + h) * HD + d) * LT + CTXL + s0 + soff] =
              __float2bfloat16(stage[soff * 129 + d]);
        }
      }
    }
  }
#undef lAp
#undef lBp
}

// ---------------- GEMM: C[M][N] = A[M][K] * BT[N][K]^T (out-proj) ---------
// R17's 3-buffer 2-phase structure (measured best for this geometry; the
// 4-phase port at BN=128 regressed -11us in R19: 8-MFMA phase grain too
// small for the barrier density).
template <typename OT>
__global__ __launch_bounds__(512, 1) void gemm_bt(const bf16* __restrict__ A,
                                                  const bf16* __restrict__ BT,
                                                  OT* __restrict__ C, int M, int N,
                                                  int K) {
  __shared__ __attribute__((aligned(16))) bf16 lA[3][256][64];  // 96 KB
  __shared__ __attribute__((aligned(16))) bf16 lB[3][128][64];  // 48 KB
  const int t = threadIdx.x;
  const int lane = t & 63, w = t >> 6;
  const int wr = w >> 1, wc = w & 1;
  const int lrow = lane & 15, kgrp = lane >> 4;
  const int rchk = lrow & 7;
  const int lin = blockIdx.y * gridDim.x + blockIdx.x;
  const int qq = (gridDim.x * gridDim.y) >> 3;
  const int swz = (lin & 7) * qq + (lin >> 3);
  const int bx = swz % gridDim.x, by = swz / gridDim.x;
  const int m0 = by * 256, n0 = bx * 128;
  const int srow = lane >> 3;
  const int schk = (lane & 7) ^ srow;
  const f32x4 fz = {0.f, 0.f, 0.f, 0.f};
  f32x4 acc[4][4];
#pragma unroll
  for (int i = 0; i < 4; ++i)
#pragma unroll
    for (int j = 0; j < 4; ++j) acc[i][j] = fz;
  const int NTK = K >> 6;

#define GSTAGE(ib, kt)                                                      \
  do {                                                                      \
    _Pragma("unroll") for (int c = 0; c < 4; ++c) {                         \
      int ra = c * 64 + w * 8 + srow;                                       \
      gload_lds16(A + (size_t)(m0 + ra) * K + (kt)*64 + schk * 8,           \
                  &lA[ib][c * 64 + w * 8][0]);                              \
    }                                                                       \
    _Pragma("unroll") for (int c = 0; c < 2; ++c) {                         \
      int rb = c * 64 + w * 8 + srow;                                       \
      gload_lds16(BT + (size_t)(n0 + rb) * K + (kt)*64 + schk * 8,          \
                  &lB[ib][c * 64 + w * 8][0]);                              \
    }                                                                       \
  } while (0)

  GSTAGE(0, 0);
  GSTAGE(1, 1);
  int ib = 0;
  for (int kt = 0; kt < NTK; ++kt) {
    if (kt + 1 < NTK)
      asm volatile("s_waitcnt vmcnt(6) lgkmcnt(0)" ::: "memory");
    else
      asm volatile("s_waitcnt vmcnt(0) lgkmcnt(0)" ::: "memory");
    __builtin_amdgcn_s_barrier();
    __builtin_amdgcn_sched_barrier(0);
    if (kt + 2 < NTK) {
      int ib2 = ib + 2;
      if (ib2 >= 3) ib2 -= 3;
      GSTAGE(ib2, kt + 2);
    }
#pragma unroll
    for (int kk = 0; kk < 2; ++kk) {
      s16x8 af[4], bf[4];
#pragma unroll
      for (int i = 0; i < 4; ++i)
        af[i] = *(const s16x8*)&lA[ib][wr * 64 + i * 16 + lrow]
                                     [(((kk << 2) + kgrp) ^ rchk) * 8];
#pragma unroll
      for (int j = 0; j < 4; ++j)
        bf[j] = *(const s16x8*)&lB[ib][wc * 64 + j * 16 + lrow]
                                     [(((kk << 2) + kgrp) ^ rchk) * 8];
      __builtin_amdgcn_s_setprio(1);
#pragma unroll
      for (int i = 0; i < 4; ++i)
#pragma unroll
        for (int j = 0; j < 4; ++j) acc[i][j] = MFMA(af[i], bf[j], acc[i][j]);
      __builtin_amdgcn_s_setprio(0);
    }
    ++ib;
    if (ib >= 3) ib = 0;
  }
#undef GSTAGE

#pragma unroll
  for (int i = 0; i < 4; ++i)
#pragma unroll
    for (int j = 0; j < 4; ++j)
#pragma unroll
      for (int r = 0; r < 4; ++r) {
        int row = m0 + wr * 64 + i * 16 + kgrp * 4 + r;
        int col = n0 + wc * 64 + j * 16 + lrow;
        float v = acc[i][j][r];
        if constexpr (sizeof(OT) == 2)
          C[(size_t)row * N + col] = __float2bfloat16(v);
        else
          C[(size_t)row * N + col] = v;
      }
}

// ---------------- flash attention (KVBLK=128, K+V double-buffered) --------
#define PSTR 72  // P row stride in elements: 144B = 16B-aligned
#define KVB 128
#define NTT 24   // LT / 128
#define SCALE2 0.1275174335919605f  // scale * log2(e)

__global__ __launch_bounds__(512, 2) void flash_attn(
    const bf16* __restrict__ qkv, const float* __restrict__ cosT,
    const float* __restrict__ sinT, const bf16* __restrict__ Kf,
    const bf16* __restrict__ Vt, bf16* __restrict__ O) {
  __shared__ __attribute__((aligned(16))) bf16 Kl[2][128][128];     // 64 KB
  __shared__ __attribute__((aligned(16))) bf16 Vl[2][128][128];     // 64 KB
  __shared__ __attribute__((aligned(16))) bf16 P_lds[8][16][PSTR];  // 18 KB
  const int t = threadIdx.x, lane = t & 63, w = t >> 6;
  // XCD panel swizzle (bijective): b=id>>6, hk=id&7, h=(hk<<1)|bit5, qb=bits3-4
  const int id = blockIdx.x;
  const int b = id >> 6, hk = id & 7;
  const int h = (hk << 1) | ((id >> 5) & 1);
  const int qb = (id >> 3) & 3;
  const int lrow = lane & 15, kgrp = lane >> 4;
  const bf16* Kp = Kf + (size_t)(b * NKV + hk) * LT * HD;
  const bf16* Vp = Vt + (size_t)(b * NKV + hk) * HD * LT;

  // prologue: load Q rows from qkv and apply RoPE in-register
  s16x8 qf[2][4];
#pragma unroll
  for (int f = 0; f < 2; ++f) {
    int srw_i = qb * 256 + w * 32 + f * 16 + lrow;
    const bf16* qrow = qkv + ((size_t)b * SS + srw_i) * QKVN + h * HD;
    s16x8 qr[4];
#pragma unroll
    for (int kd = 0; kd < 4; ++kd)
      qr[kd] = *(const s16x8*)&qrow[kd * 32 + kgrp * 8];
    const float* crow = cosT + srw_i * 64 + kgrp * 8;
    const float* srow = sinT + srw_i * 64 + kgrp * 8;
    float qv[4][8], cc[2][8], ssv[2][8];
#pragma unroll
    for (int kd = 0; kd < 4; ++kd)
#pragma unroll
      for (int j = 0; j < 8; ++j) qv[kd][j] = bf2f(qr[kd][j]);
#pragma unroll
    for (int g = 0; g < 2; ++g)
#pragma unroll
      for (int j = 0; j < 8; ++j) {
        cc[g][j] = crow[g * 32 + j];
        ssv[g][j] = srow[g * 32 + j];
      }
    bf16 o[4][8];
#pragma unroll
    for (int j = 0; j < 8; ++j) {
      o[0][j] = __float2bfloat16(qv[0][j] * cc[0][j] - qv[2][j] * ssv[0][j]);
      o[1][j] = __float2bfloat16(qv[1][j] * cc[1][j] - qv[3][j] * ssv[1][j]);
      o[2][j] = __float2bfloat16(qv[2][j] * cc[0][j] + qv[0][j] * ssv[0][j]);
      o[3][j] = __float2bfloat16(qv[3][j] * cc[1][j] + qv[1][j] * ssv[1][j]);
    }
#pragma unroll
    for (int kd = 0; kd < 4; ++kd) __builtin_memcpy(&qf[f][kd], o[kd], 16);
  }

  const f32x4 fz = {0.f, 0.f, 0.f, 0.f};
  f32x4 acc[2][8];
#pragma unroll
  for (int f = 0; f < 2; ++f)
#pragma unroll
    for (int i = 0; i < 8; ++i) acc[f][i] = fz;
  float m_[2] = {-1e30f, -1e30f}, l_[2] = {0.f, 0.f};

#define STAGE_K(buf, l0)                                                        \
  do {                                                                          \
    _Pragma("unroll") for (int c = 0; c < 4; ++c) {                             \
      int row = w * 16 + c * 4 + (lane >> 4);                                   \
      gload_lds16(Kp + (size_t)((l0) + row) * HD + ((lane & 15) ^ (row & 15)) * 8, \
                  &Kl[buf][w * 16 + c * 4][0]);                                 \
    }                                                                           \
  } while (0)
#define STAGE_V(buf, l0)                                                        \
  do {                                                                          \
    _Pragma("unroll") for (int c = 0; c < 4; ++c) {                             \
      int d = w * 16 + c * 4 + (lane >> 4);                                     \
      gload_lds16(Vp + (size_t)d * LT + (l0) + ((lane & 15) ^ (d & 15)) * 8,    \
                  &Vl[buf][w * 16 + c * 4][0]);                                 \
    }                                                                           \
  } while (0)

  STAGE_K(0, 0);
  STAGE_V(0, 0);
  __syncthreads();

  for (int tt = 0; tt < NTT; ++tt) {
    const int cur = tt & 1;
    if (tt + 1 < NTT) {
      STAGE_K(cur ^ 1, (tt + 1) * KVB);
      STAGE_V(cur ^ 1, (tt + 1) * KVB);
    }

    f32x4 sc[2][8];
#pragma unroll
    for (int f = 0; f < 2; ++f)
#pragma unroll
      for (int cf = 0; cf < 8; ++cf) sc[f][cf] = fz;
#pragma unroll
    for (int cf = 0; cf < 8; ++cf)
#pragma unroll
      for (int kd = 0; kd < 4; ++kd) {
        s16x8 kb =
            *(const s16x8*)&Kl[cur][cf * 16 + lrow][((kd * 4 + kgrp) ^ lrow) * 8];
#pragma unroll
        for (int f = 0; f < 2; ++f) sc[f][cf] = MFMA(kb, qf[f][kd], sc[f][cf]);
      }

    float mxv[2];
#pragma unroll
    for (int f = 0; f < 2; ++f) {
      float mx = sc[f][0][0];
#pragma unroll
      for (int cf = 0; cf < 8; ++cf)
#pragma unroll
        for (int r = 0; r < 4; ++r) mx = fmaxf(mx, sc[f][cf][r]);
      mx *= SCALE2;
      mx = fmaxf(mx, __shfl_xor(mx, 16, 64));
      mx = fmaxf(mx, __shfl_xor(mx, 32, 64));
      mxv[f] = mx;
    }
    bool nb = (mxv[0] > m_[0] + 8.f) || (mxv[1] > m_[1] + 8.f);
    if (__any(nb)) {
#pragma unroll
      for (int f = 0; f < 2; ++f) {
        float mn = fmaxf(m_[f], mxv[f]);
        float so = exp2f(m_[f] - mn);
        m_[f] = mn;
        l_[f] *= so;
        float sob[4];
#pragma unroll
        for (int r = 0; r < 4; ++r) sob[r] = __shfl(so, kgrp * 4 + r, 16);
#pragma unroll
        for (int nd = 0; nd < 8; ++nd)
#pragma unroll
          for (int r = 0; r < 4; ++r) acc[f][nd][r] *= sob[r];
      }
    }

    float lp[2] = {0.f, 0.f};
#pragma unroll
    for (int half = 0; half < 2; ++half) {
      s16x8 pa[2][2];
#pragma unroll
      for (int f = 0; f < 2; ++f) {
#pragma unroll
        for (int cf = 0; cf < 4; ++cf) {
          int cfs = half * 4 + cf;
          bf16 pk[4];
#pragma unroll
          for (int r = 0; r < 4; ++r) {
            float p = exp2f(sc[f][cfs][r] * SCALE2 - m_[f]);
            lp[f] += p;
            pk[r] = __float2bfloat16(p);
          }
          __builtin_memcpy((void*)&P_lds[w][lrow][cf * 16 + kgrp * 4], pk, 8);
        }
#pragma unroll
        for (int kc = 0; kc < 2; ++kc)
          pa[f][kc] = *(const s16x8*)&P_lds[w][lrow][kc * 32 + kgrp * 8];
      }
#pragma unroll
      for (int nd = 0; nd < 8; ++nd)
#pragma unroll
        for (int kc = 0; kc < 2; ++kc) {
          s16x8 vb = *(const s16x8*)&Vl[cur][nd * 16 + lrow]
                                       [((half * 8 + kc * 4 + kgrp) ^ lrow) * 8];
#pragma unroll
          for (int f = 0; f < 2; ++f) acc[f][nd] = MFMA(pa[f][kc], vb, acc[f][nd]);
        }
    }
#pragma unroll
    for (int f = 0; f < 2; ++f) l_[f] += lp[f];

    __syncthreads();  // drains K/V(t+1) DMA; protects cur bufs for next stage
  }
#undef STAGE_K
#undef STAGE_V

  float li[2][4];
#pragma unroll
  for (int f = 0; f < 2; ++f) {
    float lv = l_[f];
    lv += __shfl_xor(lv, 16, 64);
    lv += __shfl_xor(lv, 32, 64);
#pragma unroll
    for (int r = 0; r < 4; ++r) li[f][r] = 1.f / __shfl(lv, kgrp * 4 + r, 16);
  }
#pragma unroll
  for (int f = 0; f < 2; ++f)
#pragma unroll
    for (int nd = 0; nd < 8; ++nd)
#pragma unroll
      for (int r = 0; r < 4; ++r) {
        int row = qb * 256 + w * 32 + f * 16 + kgrp * 4 + r;
        O[((size_t)b * SS + row) * 2048 + h * HD + nd * 16 + lrow] =
            __float2bfloat16(acc[f][nd][r] * li[f][r]);
      }
}

// ---------------- launch ----------------

extern "C" void kernel_launch(void* const* d_in, const int* in_sizes, int n_in,
                              void* d_out, int out_size, void* d_ws, size_t ws_size,
                              hipStream_t stream) {
  const float* hs = (const float*)d_in[0];
  const float* Wqkv = (const float*)d_in[1];
  const float* Wo = (const float*)d_in[2];
  const float* ctx_k = (const float*)d_in[3];
  const float* ctx_v = (const float*)d_in[4];
  const int* pid = (const int*)d_in[5];
  float* out = (float*)d_out;
  char* ws = (char*)d_ws;

  bf16* Hb = (bf16*)(ws);                      // 16.78 MB (reused as attn_out)
  bf16* WqT = (bf16*)(ws + 16777216);          // 16.78 MB
  bf16* WoT = (bf16*)(ws + 33554432);          // 8.39 MB
  bf16* qkv = (bf16*)(ws + 41943040);          // 33.55 MB (only Q half written)
  bf16* Kfull = (bf16*)(ws + 92274688);        // 25.17 MB
  bf16* Vt = (bf16*)(ws + 117440512);          // 25.17 MB
  float* cosT = (float*)(ws + 142606336);      // 256 KB
  float* sinT = (float*)(ws + 142606336 + 262144);
  bf16* attn = Hb;  // alias: Hb dead after QKV GEMM

  prep1<<<P1_CV, 256, 0, stream>>>(hs, Wqkv, Wo, ctx_k, ctx_v, pid, Hb, WqT, WoT,
                                   Kfull, Vt, cosT, sinT);
  gemm_qkv<<<dim3(QKVN / 256, MROWS / 256), 512, 0, stream>>>(
      Hb, WqT, qkv, Kfull, Vt, cosT, sinT);
  flash_attn<<<256, 512, 0, stream>>>(qkv, cosT, sinT, Kfull, Vt, attn);
  gemm_bt<float><<<dim3(2048 / 128, MROWS / 256), 512, 0, stream>>>(
      attn, WoT, out, MROWS, 2048, HID);
}